// Round 7
// baseline (2190.188 us; speedup 1.0000x reference)
//
#include <hip/hip_runtime.h>

// Natural cubic spline coefficients, 3 rotated sweeps, LDS line-staged.
// Each sweep: (A=257, Q) -> (Q, NO=259). Block owns TL=60 full lines:
//   P1 stage 60x257 inputs in LDS (input read EXACTLY once, coalesced)
//   P2 each thread: 50-float reg window -> 16-output groups (scalar weights)
//   P3 results -> LDS as complete 259-float rows
//   P4 one contiguous 62160B coalesced float4 store (16B aligned: 60*259*4%16==0)
// Fixes round-6 counters: FETCH 124->~69MB (jb-overlap gone), WRITE 98->~69MB
// (no partial-cache-line runs).

#define NT 50    // taps window per 16-output group
#define NO 259
#define TL 60    // lines per block
#define NG 5     // max j-groups per wave (wave0: jb=0,4,8,12,16)

__device__ __host__ inline int win_base(int jb) {
    int b = 16 * jb - 17;
    return b < 0 ? 0 : (b > 207 ? 207 : b);
}

// U[j][k] (k=0..49): weight of y[win_base(j/16)+k] in output c[j], exact fp64
// inverse of tridiag(1,4,1) (m=255) with all boundary rows folded in.
__global__ void build_u_kernel(float* __restrict__ U) {
    __shared__ double th[256];
    if (threadIdx.x == 0) {
        th[0] = 1.0; th[1] = 4.0;
        for (int k = 2; k < 256; ++k) th[k] = 4.0 * th[k - 1] - th[k - 2];
    }
    __syncthreads();
    const double thm = th[255];
    auto T = [&](int i, int t) -> double {
        int a = i < t ? i : t;
        int b = i < t ? t : i;
        double v = th[a] * th[254 - b] / thm;
        return ((i + t) & 1) ? -v : v;
    };
    for (int idx = threadIdx.x; idx < NO * NT; idx += blockDim.x) {
        int j  = idx / NT;
        int k  = idx - j * NT;
        int m  = win_base(j / 16) + k;
        double w;
        if (j == 1) {
            w = (m == 0)   ? 1.0 / 6.0 : 0.0;
        } else if (j == 257) {
            w = (m == 256) ? 1.0 / 6.0 : 0.0;
        } else {
            int i = (j == 0) ? 0 : ((j == 258) ? 254 : j - 2);
            double S = 0.0;
            if (m >= 1 && m <= 255) S += T(i, m - 1);
            if (m == 0)             S -= T(i, 0)   / 6.0;
            if (m == 256)           S -= T(i, 254) / 6.0;
            if (j == 0)        w = (m == 0   ? 2.0 / 6.0 : 0.0) - S;
            else if (j == 258) w = (m == 256 ? 2.0 / 6.0 : 0.0) - S;
            else               w = S;
        }
        U[idx] = (float)w;
    }
}

template <int Q>
__global__ __launch_bounds__(256, 2) void sweep_lds(const float* __restrict__ in,
                                                    float* __restrict__ out,
                                                    const float* __restrict__ U) {
    __shared__ float lds[TL * NO];           // 15540 floats = 62160B; 2 blocks/CU
    const int t    = threadIdx.x;
    const int lane = t & 63;
    const int wv   = t >> 6;                 // 0..3 = jseg (wave-uniform)
    const int line = lane < TL ? lane : TL - 1;   // 4 dup lanes/wave (6% waste)
    const int q0   = blockIdx.x * TL;

    // ---- P1: stage lines. lds[line*257 + a]; lanes->consecutive q (coalesced).
    {
        int q  = q0 + line;
        int qc = q < Q ? q : Q - 1;
        const float* __restrict__ src = in + qc;
#pragma unroll 8
        for (int a = wv; a < 257; a += 4)
            lds[line * 257 + a] = src[(size_t)a * Q];   // stride 257: conflict-free
    }
    __syncthreads();

    // ---- P2: compute. Groups jb = wv + 4g (uniform per wave -> scalar weights).
    float res[NG][16];
#pragma unroll
    for (int g = 0; g < NG; ++g) {
        int jb = wv + 4 * g;
        if (jb < 17) {
            int base = win_base(jb);
            float win[NT];
#pragma unroll
            for (int k = 0; k < NT; ++k)
                win[k] = lds[line * 257 + base + k];    // stride 257: conflict-free
            const float* __restrict__ w = U + (size_t)jb * 16 * NT;
#pragma unroll
            for (int r = 0; r < 16; ++r) {
                if (jb * 16 + r < NO) {
                    float s = 0.f;
#pragma unroll
                    for (int k = 0; k < NT; ++k)
                        s = fmaf(w[r * NT + k], win[k], s);
                    res[g][r] = s;
                }
            }
        }
    }
    __syncthreads();

    // ---- P3: results -> LDS rows. lds[line*259 + j]; stride 259: conflict-free.
#pragma unroll
    for (int g = 0; g < NG; ++g) {
        int jb = wv + 4 * g;
        if (jb < 17) {
#pragma unroll
            for (int r = 0; r < 16; ++r) {
                int j = jb * 16 + r;
                if (j < NO) lds[line * NO + j] = res[g][r];
            }
        }
    }
    __syncthreads();

    // ---- P4: one contiguous coalesced store of the block's rows.
    int nl = Q - q0; if (nl > TL) nl = TL;
    float* __restrict__ dst = out + (size_t)q0 * NO;
    if (nl == TL) {
        // 15540 floats = 3885 float4 (base 16B-aligned: q0*259*4 % 16 == 0)
        const float4* l4 = (const float4*)lds;
        float4* d4 = (float4*)dst;
#pragma unroll
        for (int i = 0; i < 15; ++i) d4[t + 256 * i] = l4[t + 256 * i];
        if (t < 45) d4[3840 + t] = l4[3840 + t];
    } else {
        int count = nl * NO;
        for (int f = t; f < count; f += 256) dst[f] = lds[f];
    }
}

extern "C" void kernel_launch(void* const* d_in, const int* in_sizes, int n_in,
                              void* d_out, int out_size, void* d_ws, size_t ws_size,
                              hipStream_t stream) {
    const float* Y = (const float*)d_in[0];
    float* out = (float*)d_out;
    float* U   = (float*)d_ws;
    float* A2  = (float*)((char*)d_ws + (1 << 16));   // intermediate after U table

    build_u_kernel<<<1, 256, 0, stream>>>(U);

    // S1: sweep x of (x,y,z) -> (y,z,x'), into d_out (scratch)
    {
        constexpr int Q = 257 * 257;
        sweep_lds<Q><<<(Q + TL - 1) / TL, 256, 0, stream>>>(Y, out, U);
    }
    // S2: sweep y of (y,z,x') -> (z,x',y'), into ws
    {
        constexpr int Q = 257 * 259;
        sweep_lds<Q><<<(Q + TL - 1) / TL, 256, 0, stream>>>(out, A2, U);
    }
    // S3: sweep z of (z,x',y') -> (x',y',z') = row-major final, into d_out
    {
        constexpr int Q = 259 * 259;
        sweep_lds<Q><<<(Q + TL - 1) / TL, 256, 0, stream>>>(A2, out, U);
    }
}

// Round 8
// 264.947 us; speedup vs baseline: 8.2665x; 8.2665x over previous
//
#include <hip/hip_runtime.h>

// Natural cubic spline coefficients, 3 rotated sweeps (round-6 compute
// structure: VGPR=64, no spills) + XCD-chunked dispatch remap:
// flat bid -> (xcd = bid&7, slot = bid>>3), jb = slot%17 innermost, qtiles
// contiguous per XCD. All 17 jb-blocks of a qtile run temporally adjacent on
// one XCD: input windows L2-hit (fixes FETCH 124->~70MB) and adjacent-jb
// 64B store runs merge to full cache lines in L2 (fixes WRITE 98->~69MB).

#define NT 50    // register window per thread (covers all taps of its 16 j's)
#define NO 259
#define RJ 16
#define JB17 17  // ceil(259/16)

__device__ __host__ inline int win_base(int jb) {
    int b = 16 * jb - 17;
    return b < 0 ? 0 : (b > 207 ? 207 : b);
}

// U[j][k] (k=0..49): weight of y[win_base(j/16)+k] in output c[j], exact fp64
// inverse of tridiag(1,4,1) (m=255) with all boundary rows folded in.
// T(i,t) = (-1)^(i+t) th[min] th[254-max] / th[255], th_k = 4th_{k-1}-th_{k-2}.
__global__ void build_u_kernel(float* __restrict__ U) {
    __shared__ double th[256];
    if (threadIdx.x == 0) {
        th[0] = 1.0; th[1] = 4.0;
        for (int k = 2; k < 256; ++k) th[k] = 4.0 * th[k - 1] - th[k - 2];
    }
    __syncthreads();
    const double thm = th[255];
    auto T = [&](int i, int t) -> double {
        int a = i < t ? i : t;
        int b = i < t ? t : i;
        double v = th[a] * th[254 - b] / thm;
        return ((i + t) & 1) ? -v : v;
    };
    for (int idx = threadIdx.x; idx < NO * NT; idx += blockDim.x) {
        int j  = idx / NT;
        int k  = idx - j * NT;
        int m  = win_base(j / RJ) + k;       // y-index this tap multiplies
        double w;
        if (j == 1) {
            w = (m == 0)   ? 1.0 / 6.0 : 0.0;
        } else if (j == 257) {
            w = (m == 256) ? 1.0 / 6.0 : 0.0;
        } else {
            int i = (j == 0) ? 0 : ((j == 258) ? 254 : j - 2);
            double S = 0.0;
            if (m >= 1 && m <= 255) S += T(i, m - 1);      // B[t]=y[t+1]
            if (m == 0)             S -= T(i, 0)   / 6.0;  // B[0]   -= y[0]/6
            if (m == 256)           S -= T(i, 254) / 6.0;  // B[254] -= y[256]/6
            if (j == 0)        w = (m == 0   ? 2.0 / 6.0 : 0.0) - S;
            else if (j == 258) w = (m == 256 ? 2.0 / 6.0 : 0.0) - S;
            else               w = S;
        }
        U[idx] = (float)w;
    }
}

// One rotated sweep: in (A=257, Q) outer-axis lines -> out (Q, NO).
template <int Q>
__global__ __launch_bounds__(256) void sweep_rot(const float* __restrict__ in,
                                                 float* __restrict__ out,
                                                 const float* __restrict__ U) {
    constexpr int NQ = (Q + 255) / 256;      // q-tiles
    constexpr int CQ = NQ / 8, RQ = NQ % 8;  // per-XCD chunking

    const int bid  = blockIdx.x;
    const int xcd  = bid & 7;
    const int slot = bid >> 3;
    const int nslot = (CQ + (xcd < RQ ? 1 : 0)) * JB17;
    if (slot >= nslot) return;               // block-uniform early exit
    const int qt = xcd * CQ + (xcd < RQ ? xcd : RQ) + slot / JB17;
    const int jb = slot % JB17;

    __shared__ float lds[RJ * 257];          // [j'][q_local], +1 pad vs 256
    const int t    = threadIdx.x;
    const int q    = qt * 256 + t;
    const int j0   = jb * RJ;
    const int base = win_base(jb);

    float acc[RJ];
    if (q < Q) {
        const float* __restrict__ y = in + (size_t)base * Q + q;
        float win[NT];
#pragma unroll
        for (int k = 0; k < NT; ++k) win[k] = y[(size_t)k * Q];   // coalesced
        const float* __restrict__ w = U + j0 * NT;                // wave-uniform
#pragma unroll
        for (int r = 0; r < RJ; ++r) {
            float s = 0.f;
#pragma unroll
            for (int k = 0; k < NT; ++k)
                s = fmaf(w[r * NT + k], win[k], s);
            acc[r] = s;
        }
    } else {
#pragma unroll
        for (int r = 0; r < RJ; ++r) acc[r] = 0.f;
    }
#pragma unroll
    for (int r = 0; r < RJ; ++r) lds[r * 257 + t] = acc[r];       // conflict-free
    __syncthreads();
    // store transposed: flat f = s*256+t, q' = f>>4, j' = f&15 -> 64B runs
#pragma unroll
    for (int s = 0; s < RJ; ++s) {
        int f  = s * 256 + t;
        int qp = f >> 4;
        int jp = f & 15;
        int qg = qt * 256 + qp;
        int j  = j0 + jp;
        if (qg < Q && j < NO)
            out[(size_t)qg * NO + j] = lds[jp * 257 + qp];
    }
}

template <int Q>
inline void launch_sweep(const float* in, float* out, const float* U,
                         hipStream_t stream) {
    constexpr int NQ = (Q + 255) / 256;
    constexpr int maxslots = (NQ / 8 + (NQ % 8 ? 1 : 0)) * JB17;
    sweep_rot<Q><<<8 * maxslots, 256, 0, stream>>>(in, out, U);
}

extern "C" void kernel_launch(void* const* d_in, const int* in_sizes, int n_in,
                              void* d_out, int out_size, void* d_ws, size_t ws_size,
                              hipStream_t stream) {
    const float* Y = (const float*)d_in[0];
    float* out = (float*)d_out;
    float* U   = (float*)d_ws;
    float* A2  = (float*)((char*)d_ws + (1 << 16));   // intermediate after U

    build_u_kernel<<<1, 256, 0, stream>>>(U);

    // S1: sweep x of (x,y,z) -> layout (y,z,x'), into d_out (scratch)
    launch_sweep<257 * 257>(Y, out, U, stream);
    // S2: sweep y of (y,z,x') -> layout (z,x',y'), into ws
    launch_sweep<257 * 259>(out, A2, U, stream);
    // S3: sweep z of (z,x',y') -> layout (x',y',z') = row-major final, d_out
    launch_sweep<259 * 259>(A2, out, U, stream);
}